// Round 14
// baseline (163.324 us; speedup 1.0000x reference)
//
#include <hip/hip_runtime.h>

typedef unsigned int u32;
typedef int i32x4 __attribute__((ext_vector_type(4)));
typedef int i32x16 __attribute__((ext_vector_type(16)));

// ws layout (bytes):
//   [0..3]      amax (float)
//   [64..1087]  256 partial maxima (float)
//   [2048..]    Wq2: fragment-major i8 weights, 768 KB:
//               addr = nt*24576 + ks*1024 + col*32 + kb
//               (n = nt*32+col in [0,1024), k = ks*32+kb in [0,768))
#define WQ_OFF 2048

__device__ __forceinline__ void gld16(const void* g, void* l) {
    __builtin_amdgcn_global_load_lds(
        (const __attribute__((address_space(1))) void*)g,
        (__attribute__((address_space(3))) void*)l, 16, 0, 0);
}

// ---------------------------------------------------------------------------
// absmax two-stage tree (no atomics)
// ---------------------------------------------------------------------------
__global__ __launch_bounds__(256) void amax_stage1(const float* __restrict__ W,
                                                   float* __restrict__ part) {
    int t = blockIdx.x * 256 + threadIdx.x;
    float v = 0.0f;
#pragma unroll
    for (int k = 0; k < 12; ++k) v = fmaxf(v, fabsf(W[t + (k << 16)]));
#pragma unroll
    for (int d = 32; d >= 1; d >>= 1) v = fmaxf(v, __shfl_xor(v, d));
    __shared__ float sm[4];
    if ((threadIdx.x & 63) == 0) sm[threadIdx.x >> 6] = v;
    __syncthreads();
    if (threadIdx.x == 0)
        part[blockIdx.x] = fmaxf(fmaxf(sm[0], sm[1]), fmaxf(sm[2], sm[3]));
}

__global__ __launch_bounds__(256) void amax_stage2(const float* __restrict__ part,
                                                   float* __restrict__ amax) {
    float v = part[threadIdx.x];
#pragma unroll
    for (int d = 32; d >= 1; d >>= 1) v = fmaxf(v, __shfl_xor(v, d));
    __shared__ float sm[4];
    if ((threadIdx.x & 63) == 0) sm[threadIdx.x >> 6] = v;
    __syncthreads();
    if (threadIdx.x == 0)
        amax[0] = fmaxf(fmaxf(sm[0], sm[1]), fmaxf(sm[2], sm[3]));
}

// ---------------------------------------------------------------------------
// quantize W_in [1024][768] f32 -> Wq2 fragment-major i8 (validated r9-r13)
// ---------------------------------------------------------------------------
__global__ __launch_bounds__(192) void quant_k(const float* __restrict__ W,
                                               const float* __restrict__ amax,
                                               u32* __restrict__ Wq4) {
    const int n = blockIdx.x, kd = threadIdx.x;     // kd: dword index 0..191
    float s = 127.0f / amax[0];
    float4 v = ((const float4*)(W + n * 768))[kd];
    int a0 = (int)rintf(v.x * s), a1 = (int)rintf(v.y * s);
    int a2 = (int)rintf(v.z * s), a3 = (int)rintf(v.w * s);
    u32 wq = (u32)(a0 & 0xFF) | ((u32)(a1 & 0xFF) << 8) |
             ((u32)(a2 & 0xFF) << 16) | ((u32)(a3 & 0xFF) << 24);
    const int nt = n >> 5, c = n & 31, kc = kd >> 3, kb4 = kd & 7;
    Wq4[nt * 6144 + kc * 256 + c * 8 + kb4] = wq;
}

// ---------------------------------------------------------------------------
// Fused forward — small-LDS pipelined staging at 4 blocks/CU.
// M=64 rows/block, grid 1024 -> 4 blocks/CU = 16 waves/CU (residency proven
// in r11 at this LDS scale). 256 thr = 4 waves = 2 row-strips x 2 chunk
// parities; wave (s,par) computes chunks 2j+par (both n-tiles -> af
// expansion shared by 2 MFMAs, r12-validated). B staged in 12 KB windows
// [par 2][nt 2][ks 3][1 KB], double-buffered (24 KB), 64 windows,
// stage-before-compute + ONE barrier per window (r12/r13 recipe). Barriers
// of the 4 co-resident blocks are uncorrelated -> drains hide under the
// other blocks' compute (m114). Total LDS 31.7 KB; VGPR ~60 live + 32 AGPR
// acc; amdgpu_waves_per_eu(4,4) = 4 waves/EU target (128-reg budget).
// ---------------------------------------------------------------------------
__global__ __launch_bounds__(256)
__attribute__((amdgpu_waves_per_eu(4, 4)))
void nnue_fwd(
    const float* __restrict__ x,       // [B][768], values in {0,1}
    const signed char* __restrict__ Wq2,
    const float* __restrict__ amax,
    const float* __restrict__ b_in,    // [1024]
    const float* __restrict__ W_h,     // [8][1024]
    const float* __restrict__ b_h,     // [8]
    const float* __restrict__ W_psqt,  // [768]
    float* __restrict__ out) {         // [B]

    __shared__ __align__(16) signed char bufs[2][12288];  // 24 KB
    __shared__ u32   abits[64][2][12];                    // 6 KB
    __shared__ int   bmeta[64];
    __shared__ float pmeta[64];
    __shared__ float comb[64][2];

    const int t = threadIdx.x;
    const int l = t & 63, w = t >> 6;   // 4 waves
    const int cl = l & 31, hi = l >> 5;
    const int s = w >> 1, par = w & 1;  // row-strip, chunk parity
    const size_t row0 = (size_t)blockIdx.x << 6;

    // STAGE window wn (0..63): chunk-pair j = wn>>3 (chunks 2j, 2j+1),
    // ks-group g3 = wn&7 (ks = 3*g3 .. 3*g3+2), both parities, both n-tiles.
    // Wave w stages slabs jj = w*3 .. w*3+2 (slab = 1 KB (par,nt,ks) slice).
#define STAGE(dst, wn)                                                      \
    _Pragma("unroll")                                                       \
    for (int i = 0; i < 3; ++i) {                                           \
        int jj  = w * 3 + i;                /* 0..11 */                     \
        int prl = jj >= 6 ? 1 : 0;                                          \
        int rem = jj - prl * 6;                                             \
        int ntl = rem >= 3 ? 1 : 0;                                         \
        int ksl = rem - ntl * 3;                                            \
        int cg  = ((((wn) >> 3) << 1) + prl);   /* chunk 0..15 */           \
        int ks  = (((wn) & 7) * 3) + ksl;       /* 0..23 */                 \
        gld16(Wq2 + (size_t)((cg << 1) + ntl) * 24576                       \
                  + (size_t)ks * 1024 + (l << 4),                           \
              (signed char*)(dst) + jj * 1024);                             \
    }

    STAGE(bufs[0], 0)           // window 0 in flight under the A-phase

    // ---- A phase: 4 threads per row pack x-bits, popcount, psqt ---------
    {
        const int row = t >> 2, q = t & 3;          // q: K-quarter (192 k)
        const float4* xr = (const float4*)(x + (row0 + row) * 768) + q * 48;
        const float4* pw = (const float4*)W_psqt + q * 48;
        u32 csum = 0;
        float ps = 0.0f;
#define PKB(f) ((__float_as_uint(f.x) >> 29)         |                      \
                ((__float_as_uint(f.y) >> 29) << 8)  |                      \
                ((__float_as_uint(f.z) >> 29) << 16) |                      \
                ((__float_as_uint(f.w) >> 29) << 24))
#pragma unroll
        for (int i3 = 0; i3 < 3; ++i3) {
#pragma unroll
            for (int hh = 0; hh < 2; ++hh) {
                u32 dw = 0;
#pragma unroll
                for (int dl = 0; dl < 2; ++dl) {
                    u32 m16 = 0;
#pragma unroll
                    for (int jj = 0; jj < 4; ++jj) {
                        int fi = i3 * 16 + dl * 8 + hh * 4 + jj;
                        float4 f = xr[fi], p = pw[fi];
                        u32 d = PKB(f);
                        csum += d;                  // byte sums <= 48
                        ps = fmaf(f.x, p.x, ps); ps = fmaf(f.y, p.y, ps);
                        ps = fmaf(f.z, p.z, ps); ps = fmaf(f.w, p.w, ps);
                        m16 |= ((d * 0x01020408u) >> 24) << (jj * 4);
                    }
                    dw |= m16 << (dl * 16);
                }
                abits[row][hh][3 * q + i3] = dw;
            }
        }
#undef PKB
        int cnt = (csum & 0xFF) + ((csum >> 8) & 0xFF) +
                  ((csum >> 16) & 0xFF) + (csum >> 24);
        cnt += __shfl_xor(cnt, 1); cnt += __shfl_xor(cnt, 2);
        ps  += __shfl_xor(ps, 1);  ps  += __shfl_xor(ps, 2);
        if (q == 0) { bmeta[row] = (cnt - 1) >> 2; pmeta[row] = ps; }
    }
    __syncthreads();    // abits/meta visible; window-0 stage drained

    // ---- per-lane setup -------------------------------------------------
    const int r = (s << 5) + cl;        // this lane's A row (0..63)
    u32 Ab[12];
    {
        uint4 A0 = *(const uint4*)&abits[r][hi][0];
        uint4 A1 = *(const uint4*)&abits[r][hi][4];
        uint4 A2 = *(const uint4*)&abits[r][hi][8];
        Ab[0] = A0.x; Ab[1] = A0.y; Ab[2]  = A0.z; Ab[3]  = A0.w;
        Ab[4] = A1.x; Ab[5] = A1.y; Ab[6]  = A1.z; Ab[7]  = A1.w;
        Ab[8] = A2.x; Ab[9] = A2.y; Ab[10] = A2.z; Ab[11] = A2.w;
    }

    int whoff[16];
#pragma unroll
    for (int g = 0; g < 16; ++g) {
        int er = (s << 5) + (g & 3) + ((g >> 2) << 3) + (hi << 2);
        whoff[g] = bmeta[er] << 10;             // bucket * 1024
    }

    const float sc = amax[0] * (1.0f / 127.0f);
    float rs[16];
#pragma unroll
    for (int g = 0; g < 16; ++g) rs[g] = 0.0f;

    // ---- main loop: 8 chunk-pairs x 8 windows each ----------------------
    int bufi = 0;
    for (int j = 0; j < 8; ++j) {
        i32x16 acc0 = {0,0,0,0,0,0,0,0,0,0,0,0,0,0,0,0};
        i32x16 acc1 = {0,0,0,0,0,0,0,0,0,0,0,0,0,0,0,0};
#pragma unroll
        for (int g3 = 0; g3 < 8; ++g3) {
            const int wn = (j << 3) + g3;
            if (wn < 63) STAGE(bufs[bufi ^ 1], wn + 1)

            // compute this wave's (par) chunk slice from bufs[bufi]
            const signed char* bb = bufs[bufi] + par * 6144
                                    + (cl << 5) + (hi << 4);
#pragma unroll
            for (int ksl = 0; ksl < 3; ++ksl) {
                int ks = g3 * 3 + ksl;
                u32 pr = Ab[ks >> 1];
                asm volatile("" : "+v"(pr));    // defeat hoist/CSE
                u32 m = (ks & 1) ? (pr >> 16) : (pr & 0xFFFFu);
                i32x4 af;
                af[0] = (int)(((m        & 0xFu) * 0x00204081u) & 0x01010101u);
                af[1] = (int)((((m >> 4) & 0xFu) * 0x00204081u) & 0x01010101u);
                af[2] = (int)((((m >> 8) & 0xFu) * 0x00204081u) & 0x01010101u);
                af[3] = (int)((((m >> 12)      ) * 0x00204081u) & 0x01010101u);
                i32x4 b0 = *(const i32x4*)(bb + (ksl << 10));
                i32x4 b1 = *(const i32x4*)(bb + 3072 + (ksl << 10));
                acc0 = __builtin_amdgcn_mfma_i32_32x32x32_i8(af, b0, acc0, 0, 0, 0);
                acc1 = __builtin_amdgcn_mfma_i32_32x32x32_i8(af, b1, acc1, 0, 0, 0);
            }

            if (g3 == 7) {
                // fused epilogue for chunk c = 2j + par
                const int col0 = (((j << 1) + par) << 6) + cl;
                const float bi0 = b_in[col0], bi1 = b_in[col0 + 32];
#pragma unroll
                for (int g = 0; g < 16; ++g) {
                    float h0 = fminf(fmaxf(fmaf((float)acc0[g], sc, bi0), 0.f), 1.f);
                    float h1 = fminf(fmaxf(fmaf((float)acc1[g], sc, bi1), 0.f), 1.f);
                    rs[g] = fmaf(h0, W_h[whoff[g] + col0], rs[g]);
                    rs[g] = fmaf(h1, W_h[whoff[g] + col0 + 32], rs[g]);
                }
            }
            __syncthreads();
            bufi ^= 1;
        }
    }
#undef STAGE

    // ---- reduce over 32 col-lanes, combine parities, write --------------
#pragma unroll
    for (int g = 0; g < 16; ++g) {
#pragma unroll
        for (int d = 1; d < 32; d <<= 1) rs[g] += __shfl_xor(rs[g], d);
    }
    if (cl == 0) {
#pragma unroll
        for (int g = 0; g < 16; ++g) {
            int er = (s << 5) + (g & 3) + ((g >> 2) << 3) + (hi << 2);
            comb[er][par] = rs[g];
        }
    }
    __syncthreads();
    if (t < 64) {
        out[row0 + t] = comb[t][0] + comb[t][1] + pmeta[t] + b_h[bmeta[t]];
    }
}

extern "C" void kernel_launch(void* const* d_in, const int* in_sizes, int n_in,
                              void* d_out, int out_size, void* d_ws, size_t ws_size,
                              hipStream_t stream) {
    const float* x      = (const float*)d_in[0];
    const float* W_in   = (const float*)d_in[1];
    const float* b_in   = (const float*)d_in[2];
    const float* W_h    = (const float*)d_in[3];
    const float* b_h    = (const float*)d_in[4];
    const float* W_psqt = (const float*)d_in[5];
    float* out = (float*)d_out;

    float* amax = (float*)d_ws;
    float* part = (float*)((char*)d_ws + 64);
    signed char* Wq2 = (signed char*)d_ws + WQ_OFF;     // 768 KB

    amax_stage1<<<256, 256, 0, stream>>>(W_in, part);
    amax_stage2<<<1, 256, 0, stream>>>(part, amax);
    quant_k<<<1024, 192, 0, stream>>>(W_in, amax, (u32*)Wq2);

    int B = out_size;                   // 65536
    nnue_fwd<<<B / 64, 256, 0, stream>>>(x, Wq2, amax, b_in, W_h, b_h,
                                         W_psqt, out);
}

// Round 15
// 117.593 us; speedup vs baseline: 1.3889x; 1.3889x over previous
//
#include <hip/hip_runtime.h>

typedef unsigned int u32;
typedef unsigned short u16;
typedef int i32x4 __attribute__((ext_vector_type(4)));
typedef int i32x16 __attribute__((ext_vector_type(16)));

// ws layout (bytes):
//   [0..3]      amax (float)
//   [64..1087]  256 partial maxima (float)
//   [2048..]    Wq2: fragment-major i8 weights, 768 KB:
//               addr = ntg*24576 + ks*1024 + col*32 + kb
//               (n = ntg*32+col in [0,1024), k = ks*32+kb in [0,768))
#define WQ_OFF 2048

__device__ __forceinline__ void gld16(const void* g, void* l) {
    __builtin_amdgcn_global_load_lds(
        (const __attribute__((address_space(1))) void*)g,
        (__attribute__((address_space(3))) void*)l, 16, 0, 0);
}

// ---------------------------------------------------------------------------
// absmax two-stage tree (no atomics)
// ---------------------------------------------------------------------------
__global__ __launch_bounds__(256) void amax_stage1(const float* __restrict__ W,
                                                   float* __restrict__ part) {
    int t = blockIdx.x * 256 + threadIdx.x;
    float v = 0.0f;
#pragma unroll
    for (int k = 0; k < 12; ++k) v = fmaxf(v, fabsf(W[t + (k << 16)]));
#pragma unroll
    for (int d = 32; d >= 1; d >>= 1) v = fmaxf(v, __shfl_xor(v, d));
    __shared__ float sm[4];
    if ((threadIdx.x & 63) == 0) sm[threadIdx.x >> 6] = v;
    __syncthreads();
    if (threadIdx.x == 0)
        part[blockIdx.x] = fmaxf(fmaxf(sm[0], sm[1]), fmaxf(sm[2], sm[3]));
}

__global__ __launch_bounds__(256) void amax_stage2(const float* __restrict__ part,
                                                   float* __restrict__ amax) {
    float v = part[threadIdx.x];
#pragma unroll
    for (int d = 32; d >= 1; d >>= 1) v = fmaxf(v, __shfl_xor(v, d));
    __shared__ float sm[4];
    if ((threadIdx.x & 63) == 0) sm[threadIdx.x >> 6] = v;
    __syncthreads();
    if (threadIdx.x == 0)
        amax[0] = fmaxf(fmaxf(sm[0], sm[1]), fmaxf(sm[2], sm[3]));
}

// ---------------------------------------------------------------------------
// quantize W_in [1024][768] f32 -> Wq2 fragment-major i8 (validated r9-r14)
// ---------------------------------------------------------------------------
__global__ __launch_bounds__(192) void quant_k(const float* __restrict__ W,
                                               const float* __restrict__ amax,
                                               u32* __restrict__ Wq4) {
    const int n = blockIdx.x, kd = threadIdx.x;     // kd: dword index 0..191
    float s = 127.0f / amax[0];
    float4 v = ((const float4*)(W + n * 768))[kd];
    int a0 = (int)rintf(v.x * s), a1 = (int)rintf(v.y * s);
    int a2 = (int)rintf(v.z * s), a3 = (int)rintf(v.w * s);
    u32 wq = (u32)(a0 & 0xFF) | ((u32)(a1 & 0xFF) << 8) |
             ((u32)(a2 & 0xFF) << 16) | ((u32)(a3 & 0xFF) << 24);
    const int nt = n >> 5, c = n & 31, kc = kd >> 3, kb4 = kd & 7;
    Wq4[nt * 6144 + kc * 256 + c * 8 + kb4] = wq;
}

// ---------------------------------------------------------------------------
// Fused forward — r12's pipelined-window schedule, re-geometried for waves.
// M=64 rows/block, grid 1024. 256 thr = 4 waves = 2 row-strips x 2
// chunk-halves (wave (s,nh) computes chunks nh*8..nh*8+7, BOTH n-tiles ->
// af expansion shared by 2 MFMAs, r12-validated). B staged in 16 KB windows
// [nh 2][nt 2][kc 4][1 KB], double-buffered (32 KB), 48 windows,
// stage-before-compute + ONE barrier per window. A-phase: each lane loads a
// QUARTER row (x read once/block), bits exchanged via 6 KB LDS panel.
// Total LDS 39.5 KB -> 4 blocks/CU by LDS; waves_per_eu(3,4): min-3 ->
// ~170-reg unified budget -> no spill (live ~132 incl AGPR acc).
// Residency = min(grid 4, LDS 4, regs ~3.8) = 3-4 blocks -> 12-16 waves/CU.
// ---------------------------------------------------------------------------
__global__ __launch_bounds__(256)
__attribute__((amdgpu_waves_per_eu(3, 4)))
void nnue_fwd(
    const float* __restrict__ x,       // [B][768], values in {0,1}
    const signed char* __restrict__ Wq2,
    const float* __restrict__ amax,
    const float* __restrict__ b_in,    // [1024]
    const float* __restrict__ W_h,     // [8][1024]
    const float* __restrict__ b_h,     // [8]
    const float* __restrict__ W_psqt,  // [768]
    float* __restrict__ out) {         // [B]

    __shared__ __align__(16) signed char bufs[2][16384];  // 32 KB
    __shared__ __align__(16) u16 abits16[64][2][24];      // 6 KB [row][hi][ks]
    __shared__ int   cntp[64][2];
    __shared__ float psp[64][2];
    __shared__ float comb[64][2];

    const int t = threadIdx.x;
    const int l = t & 63, w = t >> 6;   // 4 waves
    const int cl = l & 31, hi = l >> 5;
    const int s = w >> 1, nh = w & 1;   // row-strip, chunk-half
    const size_t row0 = (size_t)blockIdx.x << 6;
    const int r = (s << 5) + cl;        // this lane's A row (0..63)

    // STAGE window wn (0..47): chunk-pair cp = wn/6, kc-group kq = wn%6
    // (ks = kq*4 + [0..4)) for chunks {cp, cp+8}, both n-tiles.
    // 16 slabs of 1 KB; wave w stages slabs j = w*4 .. w*4+3.
#define STAGE(dst, wn)                                                      \
    _Pragma("unroll")                                                       \
    for (int i = 0; i < 4; ++i) {                                           \
        int jj  = w * 4 + i;                /* 0..15 */                     \
        int nhg = jj >> 3;                                                  \
        int ntl = (jj >> 2) & 1;                                            \
        int kcl = jj & 3;                                                   \
        int cg  = nhg * 8 + ((wn) / 6);     /* chunk 0..15 */               \
        int ks  = ((wn) % 6) * 4 + kcl;     /* 0..23 */                     \
        gld16(Wq2 + (size_t)((cg << 1) + ntl) * 24576                       \
                  + (size_t)ks * 1024 + (l << 4),                           \
              (signed char*)(dst) + jj * 1024);                             \
    }

    STAGE(bufs[0], 0)           // window 0 in flight under the A-phase

    // ---- A phase: lane covers quarter-row (r, k in nh*384+hi*16-comb) ---
    {
        const float4* xr = (const float4*)(x + (row0 + r) * 768);
        const float4* pw = (const float4*)W_psqt;
        u32 csum = 0;
        float ps = 0.0f;
#define PKB(f) ((__float_as_uint(f.x) >> 29)         |                      \
                ((__float_as_uint(f.y) >> 29) << 8)  |                      \
                ((__float_as_uint(f.z) >> 29) << 16) |                      \
                ((__float_as_uint(f.w) >> 29) << 24))
#define DOT4(f, q) ps = fmaf(f.x, q.x, ps); ps = fmaf(f.y, q.y, ps);        \
                   ps = fmaf(f.z, q.z, ps); ps = fmaf(f.w, q.w, ps);
#pragma unroll
        for (int k12 = 0; k12 < 12; ++k12) {
            int fi = nh * 96 + k12 * 8 + hi * 4;    // float4 index
            float4 f0 = xr[fi + 0], f1 = xr[fi + 1];
            float4 f2 = xr[fi + 2], f3 = xr[fi + 3];
            float4 p0 = pw[fi + 0], p1 = pw[fi + 1];
            float4 p2 = pw[fi + 2], p3 = pw[fi + 3];
            u32 d0 = PKB(f0), d1 = PKB(f1), d2 = PKB(f2), d3 = PKB(f3);
            csum += d0 + d1 + d2 + d3;              // byte-lane sums <= 48
            DOT4(f0, p0) DOT4(f1, p1) DOT4(f2, p2) DOT4(f3, p3)
            u32 m16 = ((d0 * 0x01020408u) >> 24)
                    | (((d1 * 0x01020408u) >> 24) << 4)
                    | (((d2 * 0x01020408u) >> 24) << 8)
                    | (((d3 * 0x01020408u) >> 24) << 12);
            abits16[r][hi][nh * 12 + k12] = (u16)m16;
        }
#undef DOT4
#undef PKB
        int cnt = (csum & 0xFF) + ((csum >> 8) & 0xFF) +
                  ((csum >> 16) & 0xFF) + (csum >> 24);
        cnt += __shfl_xor(cnt, 32);     // combine hi halves (same r, nh)
        ps  += __shfl_xor(ps, 32);
        if (hi == 0) { cntp[r][nh] = cnt; psp[r][nh] = ps; }
    }
    __syncthreads();    // abits/cnt/ps visible; window-0 stage drained

    // ---- per-lane setup -------------------------------------------------
    u32 Ab[12];
    {
        const uint4* ap = (const uint4*)&abits16[r][hi][0];
        uint4 A0 = ap[0], A1 = ap[1], A2 = ap[2];
        Ab[0] = A0.x; Ab[1] = A0.y; Ab[2]  = A0.z; Ab[3]  = A0.w;
        Ab[4] = A1.x; Ab[5] = A1.y; Ab[6]  = A1.z; Ab[7]  = A1.w;
        Ab[8] = A2.x; Ab[9] = A2.y; Ab[10] = A2.z; Ab[11] = A2.w;
    }

    int whoff[16];
#pragma unroll
    for (int g = 0; g < 16; ++g) {
        int er = (s << 5) + (g & 3) + ((g >> 2) << 3) + (hi << 2);
        int cnt = cntp[er][0] + cntp[er][1];
        whoff[g] = ((cnt - 1) >> 2) << 10;      // bucket * 1024
    }

    const float sc = amax[0] * (1.0f / 127.0f);
    float rs[16];
#pragma unroll
    for (int g = 0; g < 16; ++g) rs[g] = 0.0f;

    // ---- main loop: 8 chunk-pairs x 6 windows each ----------------------
    int bufi = 0;
    for (int cp = 0; cp < 8; ++cp) {
        i32x16 acc0 = {0,0,0,0,0,0,0,0,0,0,0,0,0,0,0,0};
        i32x16 acc1 = {0,0,0,0,0,0,0,0,0,0,0,0,0,0,0,0};
#pragma unroll
        for (int kq = 0; kq < 6; ++kq) {
            const int wn = cp * 6 + kq;
            if (wn < 47) STAGE(bufs[bufi ^ 1], wn + 1)

            // compute this wave's (nh) chunk slice from bufs[bufi]
            const signed char* bb = bufs[bufi] + nh * 8192
                                    + (cl << 5) + (hi << 4);
#pragma unroll
            for (int kcl = 0; kcl < 4; ++kcl) {
                int ks = kq * 4 + kcl;
                u32 pr = Ab[ks >> 1];
                asm volatile("" : "+v"(pr));    // defeat hoist/CSE
                u32 m = (ks & 1) ? (pr >> 16) : (pr & 0xFFFFu);
                i32x4 af;
                af[0] = (int)(((m        & 0xFu) * 0x00204081u) & 0x01010101u);
                af[1] = (int)((((m >> 4) & 0xFu) * 0x00204081u) & 0x01010101u);
                af[2] = (int)((((m >> 8) & 0xFu) * 0x00204081u) & 0x01010101u);
                af[3] = (int)((((m >> 12)      ) * 0x00204081u) & 0x01010101u);
                i32x4 b0 = *(const i32x4*)(bb + (kcl << 10));
                i32x4 b1 = *(const i32x4*)(bb + 4096 + (kcl << 10));
                acc0 = __builtin_amdgcn_mfma_i32_32x32x32_i8(af, b0, acc0, 0, 0, 0);
                acc1 = __builtin_amdgcn_mfma_i32_32x32x32_i8(af, b1, acc1, 0, 0, 0);
            }

            if (kq == 5) {
                // fused epilogue for chunk c = nh*8 + cp
                const int col0 = ((nh << 3) + cp << 6) + cl;
                const float bi0 = b_in[col0], bi1 = b_in[col0 + 32];
#pragma unroll
                for (int g = 0; g < 16; ++g) {
                    float h0 = fminf(fmaxf(fmaf((float)acc0[g], sc, bi0), 0.f), 1.f);
                    float h1 = fminf(fmaxf(fmaf((float)acc1[g], sc, bi1), 0.f), 1.f);
                    rs[g] = fmaf(h0, W_h[whoff[g] + col0], rs[g]);
                    rs[g] = fmaf(h1, W_h[whoff[g] + col0 + 32], rs[g]);
                }
            }
            __syncthreads();
            bufi ^= 1;
        }
    }
#undef STAGE

    // ---- reduce over 32 col-lanes, combine chunk-halves, write ----------
#pragma unroll
    for (int g = 0; g < 16; ++g) {
#pragma unroll
        for (int d = 1; d < 32; d <<= 1) rs[g] += __shfl_xor(rs[g], d);
    }
    if (cl == 0) {
#pragma unroll
        for (int g = 0; g < 16; ++g) {
            int er = (s << 5) + (g & 3) + ((g >> 2) << 3) + (hi << 2);
            comb[er][nh] = rs[g];
        }
    }
    __syncthreads();
    if (t < 64) {
        int cnt = cntp[t][0] + cntp[t][1];
        out[row0 + t] = comb[t][0] + comb[t][1] + psp[t][0] + psp[t][1]
                        + b_h[(cnt - 1) >> 2];
    }
}

extern "C" void kernel_launch(void* const* d_in, const int* in_sizes, int n_in,
                              void* d_out, int out_size, void* d_ws, size_t ws_size,
                              hipStream_t stream) {
    const float* x      = (const float*)d_in[0];
    const float* W_in   = (const float*)d_in[1];
    const float* b_in   = (const float*)d_in[2];
    const float* W_h    = (const float*)d_in[3];
    const float* b_h    = (const float*)d_in[4];
    const float* W_psqt = (const float*)d_in[5];
    float* out = (float*)d_out;

    float* amax = (float*)d_ws;
    float* part = (float*)((char*)d_ws + 64);
    signed char* Wq2 = (signed char*)d_ws + WQ_OFF;     // 768 KB

    amax_stage1<<<256, 256, 0, stream>>>(W_in, part);
    amax_stage2<<<1, 256, 0, stream>>>(part, amax);
    quant_k<<<1024, 192, 0, stream>>>(W_in, amax, (u32*)Wq2);

    int B = out_size;                   // 65536
    nnue_fwd<<<B / 64, 256, 0, stream>>>(x, Wq2, amax, b_in, W_h, b_h,
                                         W_psqt, out);
}